// Round 1
// baseline (1187.860 us; speedup 1.0000x reference)
//
#include <hip/hip_runtime.h>
#include <hip/hip_bf16.h>

// Problem constants
#define L_DIM 1024   // number of patches = 32*32 (unfold grid on 264-padded image w/ stride 8)
#define SPA   1024   // cos spatial = 32*32
#define MTOT  1089   // 33*33 output "macro pixel" grid (264 = 33*8)
#define NTOT  2048   // 32 channels * 8 ry * 8 rx

// ---------------------------------------------------------------------------
// Kernel 1: transpose cos (B,L,32,32) -> cosT[b][s=iy*32+ix][l]  (contig in l)
// ---------------------------------------------------------------------------
__global__ void transpose_cos_k(const float* __restrict__ src, float* __restrict__ dst) {
    __shared__ float tile[32][33];
    const int b  = blockIdx.z;
    const int l0 = blockIdx.x * 32;
    const int s0 = blockIdx.y * 32;
    const float* in  = src + (size_t)b * L_DIM * SPA;
    float*       out = dst + (size_t)b * L_DIM * SPA;
    const int tx = threadIdx.x, ty = threadIdx.y;
    #pragma unroll
    for (int i = ty; i < 32; i += 8)
        tile[i][tx] = in[(size_t)(l0 + i) * SPA + s0 + tx];
    __syncthreads();
    #pragma unroll
    for (int i = ty; i < 32; i += 8)
        out[(size_t)(s0 + i) * L_DIM + l0 + tx] = tile[tx][i];
}

// ---------------------------------------------------------------------------
// Kernel 2: W[b][py'][px'][n],  n = c*64 + ry*8 + rx,  py',px' in [0,33)
//   W = bpad[b,c,8py'+ry,8px'+rx] * (1 - mpad[b,0,...])   (replicate pad fused)
// ---------------------------------------------------------------------------
__global__ void build_w_k(const float* __restrict__ bsrc, const float* __restrict__ msrc,
                          float* __restrict__ w) {
    const int total = 4 * MTOT * NTOT;
    const int idx = blockIdx.x * 256 + threadIdx.x;
    if (idx >= total) return;
    const int n = idx & (NTOT - 1);
    const int t = idx >> 11;
    const int p = t % MTOT;
    const int b = t / MTOT;
    const int px = p % 33, py = p / 33;
    const int c = n >> 6, ry = (n >> 3) & 7, rx = n & 7;
    int Y = 8 * py + ry - 4;
    int X = 8 * px + rx - 4;
    Y = min(max(Y, 0), 255);
    X = min(max(X, 0), 255);
    const float bv = bsrc[(((size_t)b * 32 + c) * 256 + Y) * 256 + X];
    const float mv = msrc[((size_t)b * 256 + Y) * 256 + X];
    w[idx] = bv * (1.0f - mv);
}

// ---------------------------------------------------------------------------
// Kernel 3: per-batch GEMM  out[m=(qy,qx)][n=(c,ry,rx)] =
//   sum_{d=(dy,dx), k'=(py,px)} cosT[b][(qy-dy)*32+(qx-dx)][k'] * W[b][py+dy][px+dx][n]
// 64x64 tile, 256 threads, 4x4 per thread, fused crop epilogue.
// ---------------------------------------------------------------------------
__global__ __launch_bounds__(256) void gemm_deconv_k(const float* __restrict__ cosT,
                                                     const float* __restrict__ W,
                                                     float* __restrict__ out) {
    __shared__ float As[16][68];  // [k][m], padded to 68 for bank spread + float4 align
    __shared__ float Bs[16][64];  // [k][n]
    const int b      = blockIdx.z;
    const int n_base = blockIdx.x * 64;
    const int m_base = blockIdx.y * 64;
    const int tid = threadIdx.x;
    const int tx = tid & 15;   // -> n quad
    const int ty = tid >> 4;   // -> m quad
    float acc[4][4] = {};

    // A-loader: one row per 4 threads, 4 consecutive k per thread
    const int arow = m_base + (tid >> 2);
    const int kl   = (tid & 3) * 4;
    const int qy   = arow / 33;
    const int qx   = arow - qy * 33;
    // B-loader: row = tid>>4 (16 rows), 4 consecutive n per thread
    const int brow = tid >> 4;
    const int bcol = (tid & 15) * 4;

    for (int d = 0; d < 4; ++d) {
        const int dy = d >> 1, dx = d & 1;
        const int iy = qy - dy, ix = qx - dx;
        const bool avalid = (arow < MTOT) && ((unsigned)iy < 32u) && ((unsigned)ix < 32u);
        const float* aptr = cosT + (((size_t)b * 32 + iy) * 32 + ix) * L_DIM + kl;

        for (int k0 = 0; k0 < 1024; k0 += 16) {
            float4 av = make_float4(0.f, 0.f, 0.f, 0.f);
            if (avalid) av = *reinterpret_cast<const float4*>(aptr + k0);
            const int kp = k0 + brow;
            const int py = kp >> 5, px = kp & 31;
            const int wrow = (py + dy) * 33 + (px + dx);
            const float4 bv = *reinterpret_cast<const float4*>(
                W + ((size_t)b * MTOT + wrow) * NTOT + n_base + bcol);

            __syncthreads();   // previous tile fully consumed
            As[kl + 0][tid >> 2] = av.x;
            As[kl + 1][tid >> 2] = av.y;
            As[kl + 2][tid >> 2] = av.z;
            As[kl + 3][tid >> 2] = av.w;
            *reinterpret_cast<float4*>(&Bs[brow][bcol]) = bv;
            __syncthreads();   // tile ready

            #pragma unroll
            for (int k = 0; k < 16; ++k) {
                const float4 a  = *reinterpret_cast<const float4*>(&As[k][ty * 4]);
                const float4 bb = *reinterpret_cast<const float4*>(&Bs[k][tx * 4]);
                acc[0][0] += a.x * bb.x; acc[0][1] += a.x * bb.y;
                acc[0][2] += a.x * bb.z; acc[0][3] += a.x * bb.w;
                acc[1][0] += a.y * bb.x; acc[1][1] += a.y * bb.y;
                acc[1][2] += a.y * bb.z; acc[1][3] += a.y * bb.w;
                acc[2][0] += a.z * bb.x; acc[2][1] += a.z * bb.y;
                acc[2][2] += a.z * bb.z; acc[2][3] += a.z * bb.w;
                acc[3][0] += a.w * bb.x; acc[3][1] += a.w * bb.y;
                acc[3][2] += a.w * bb.z; acc[3][3] += a.w * bb.w;
            }
        }
    }

    // Epilogue: scatter with crop (output = full[:, :, 4:260, 4:260])
    #pragma unroll
    for (int i = 0; i < 4; ++i) {
        const int m = m_base + ty * 4 + i;
        if (m >= MTOT) continue;
        const int qy2 = m / 33, qx2 = m - qy2 * 33;
        #pragma unroll
        for (int j = 0; j < 4; ++j) {
            const int n = n_base + tx * 4 + j;
            const int c = n >> 6, ry = (n >> 3) & 7, rx = n & 7;
            const int y = qy2 * 8 + ry - 4;
            const int x = qx2 * 8 + rx - 4;
            if ((unsigned)y < 256u && (unsigned)x < 256u)
                out[(((size_t)b * 32 + c) * 256 + y) * 256 + x] = acc[i][j];
        }
    }
}

// ---------------------------------------------------------------------------
// Fallback (no workspace): direct per-output-element evaluation. Slow but correct.
// ---------------------------------------------------------------------------
__global__ void naive_deconv_k(const float* __restrict__ cosp, const float* __restrict__ bsrc,
                               const float* __restrict__ msrc, float* __restrict__ out) {
    const int idx = blockIdx.x * 256 + threadIdx.x;
    if (idx >= 4 * 32 * 256 * 256) return;
    const int x = idx & 255, y = (idx >> 8) & 255, c = (idx >> 16) & 31, b = idx >> 21;
    const int oy = y + 4, ox = x + 4;
    const int qy = oy >> 3, ry = oy & 7, qx = ox >> 3, rx = ox & 7;
    float s = 0.f;
    for (int dy = 0; dy < 2; ++dy) {
        for (int dx = 0; dx < 2; ++dx) {
            const int iy = qy - dy, ix = qx - dx;
            if ((unsigned)iy >= 32u || (unsigned)ix >= 32u) continue;
            for (int py = 0; py < 32; ++py) {
                int Y = 8 * (py + dy) + ry - 4;
                Y = min(max(Y, 0), 255);
                for (int px = 0; px < 32; ++px) {
                    int X = 8 * (px + dx) + rx - 4;
                    X = min(max(X, 0), 255);
                    const float cv = cosp[(((size_t)(b * 1024 + py * 32 + px)) * 32 + iy) * 32 + ix];
                    const float bv = bsrc[(((size_t)(b * 32 + c)) * 256 + Y) * 256 + X];
                    const float mv = msrc[((size_t)b * 65536 + (size_t)Y * 256) + X];
                    s += cv * bv * (1.f - mv);
                }
            }
        }
    }
    out[idx] = s;
}

// ---------------------------------------------------------------------------
extern "C" void kernel_launch(void* const* d_in, const int* in_sizes, int n_in,
                              void* d_out, int out_size, void* d_ws, size_t ws_size,
                              hipStream_t stream) {
    const float* cosp = (const float*)d_in[0];  // (4,1024,32,32)
    const float* bp   = (const float*)d_in[1];  // (4,32,256,256)
    const float* mp   = (const float*)d_in[2];  // (4,1,256,256)
    float* outp = (float*)d_out;                // (4,32,256,256)

    const size_t cosT_elems = (size_t)4 * L_DIM * SPA;   // 16.8 MB
    const size_t w_elems    = (size_t)4 * MTOT * NTOT;   // 35.7 MB
    const size_t need = (cosT_elems + w_elems) * sizeof(float);

    if (ws_size >= need) {
        float* cosT = (float*)d_ws;
        float* W    = cosT + cosT_elems;
        transpose_cos_k<<<dim3(32, 32, 4), dim3(32, 8), 0, stream>>>(cosp, cosT);
        const int wtot = 4 * MTOT * NTOT;
        build_w_k<<<(wtot + 255) / 256, 256, 0, stream>>>(bp, mp, W);
        gemm_deconv_k<<<dim3(32, 18, 4), dim3(256), 0, stream>>>(cosT, W, outp);
    } else {
        const int tot = 4 * 32 * 256 * 256;
        naive_deconv_k<<<(tot + 255) / 256, 256, 0, stream>>>(cosp, bp, mp, outp);
    }
}

// Round 3
// 483.318 us; speedup vs baseline: 2.4577x; 2.4577x over previous
//
#include <hip/hip_runtime.h>
#include <hip/hip_bf16.h>
#include <stdint.h>

#define L_DIM 1024
#define SPA   1024
#define MTOT  1089
#define NTOT  2048

typedef __attribute__((ext_vector_type(8))) short bf16x8;
typedef __attribute__((ext_vector_type(4))) float f32x4;

__device__ __forceinline__ unsigned short f2bf(float x) {
    __hip_bfloat16 h = __float2bfloat16(x);
    return *reinterpret_cast<unsigned short*>(&h);
}
__device__ __forceinline__ float bf2f(unsigned short u) {
    __hip_bfloat16 h;
    *reinterpret_cast<unsigned short*>(&h) = u;
    return __bfloat162float(h);
}

__device__ __forceinline__ void gload16(const void* g, void* l) {
    __builtin_amdgcn_global_load_lds(
        (const __attribute__((address_space(1))) unsigned int*)g,
        (__attribute__((address_space(3))) unsigned int*)l, 16, 0, 0);
}

// ---------------------------------------------------------------------------
// Prep 1: cos (B,L,32,32) -> cosT_hi/lo[b][s=iy*32+ix][l] (bf16, l-contiguous)
// Also zeroes the 256B zpad region (read target for invalid staging rows).
// ---------------------------------------------------------------------------
__global__ void prep_cos_k(const float* __restrict__ src,
                           unsigned short* __restrict__ hi,
                           unsigned short* __restrict__ lo,
                           float* __restrict__ zpad) {
    __shared__ float tile[32][33];
    const int b  = blockIdx.z;
    const int l0 = blockIdx.x * 32;
    const int s0 = blockIdx.y * 32;
    const float* in = src + (size_t)b * L_DIM * SPA;
    const size_t obase = (size_t)b * L_DIM * SPA;
    const int tx = threadIdx.x, ty = threadIdx.y;
    if (blockIdx.x == 0 && blockIdx.y == 0 && blockIdx.z == 0 && ty == 0) {
        zpad[tx] = 0.f; zpad[tx + 32] = 0.f;
    }
    #pragma unroll
    for (int i = ty; i < 32; i += 8)
        tile[i][tx] = in[(size_t)(l0 + i) * SPA + s0 + tx];
    __syncthreads();
    #pragma unroll
    for (int i = ty; i < 32; i += 8) {
        const float x = tile[tx][i];
        const unsigned short h = f2bf(x);
        const size_t o = obase + (size_t)(s0 + i) * L_DIM + l0 + tx;
        hi[o] = h;
        lo[o] = f2bf(x - bf2f(h));
    }
}

// ---------------------------------------------------------------------------
// Prep 2: WTx_hi/lo[b][dx][n][py'][px]  (bf16), px in [0,32) -> 64B rows
//   value = bpad[b,c, 8*py'+ry, 8*(px+dx)+rx] * (1 - mpad[...]) (clamped)
//   n = c*64 + ry*8 + rx ; py' in [0,33)
// ---------------------------------------------------------------------------
__global__ void prep_w_k(const float* __restrict__ bsrc, const float* __restrict__ msrc,
                         unsigned short* __restrict__ whi, unsigned short* __restrict__ wlo) {
    const int total = 4 * 2 * 2048 * 33 * 32;
    const int i = blockIdx.x * 256 + threadIdx.x;
    if (i >= total) return;
    const int px = i & 31;
    int t = i >> 5;
    const int py = t % 33; t /= 33;
    const int n = t & 2047; t >>= 11;
    const int dx = t & 1;
    const int b = t >> 1;
    const int c = n >> 6, ry = (n >> 3) & 7, rx = n & 7;
    int Y = 8 * py + ry - 4;        Y = min(max(Y, 0), 255);
    int X = 8 * (px + dx) + rx - 4; X = min(max(X, 0), 255);
    const float bv = bsrc[(((size_t)b * 32 + c) * 256 + Y) * 256 + X];
    const float mv = msrc[((size_t)b * 256 + Y) * 256 + X];
    const float w = bv * (1.f - mv);
    const unsigned short h = f2bf(w);
    whi[i] = h;
    wlo[i] = f2bf(w - bf2f(h));
}

// ---------------------------------------------------------------------------
// MFMA GEMM: out[m=(qy,qx)][n=(c,ry,rx)] over K = 4 d-shifts x 1024 patches,
// split-precision 3-term: (hi,hi) + (lo,hi) + (hi,lo) -> 12 phases.
// 128x128 tile, BK=32, 4 waves, 4x4 frags of mfma_f32_16x16x32_bf16.
// ---------------------------------------------------------------------------
__global__ __launch_bounds__(256, 2) void mfma_deconv_k(
    const unsigned short* __restrict__ Ahi_, const unsigned short* __restrict__ Alo_,
    const unsigned short* __restrict__ Whi_, const unsigned short* __restrict__ Wlo_,
    const float* __restrict__ zpad, float* __restrict__ out)
{
    __shared__ int lds_i[4096];            // 16 KB
    char* lds = (char*)lds_i;
    char* As = lds;                        // [128 m][32 k] bf16, slot-swizzled
    char* Bs = lds + 8192;                 // [128 n][32 k] bf16, slot-swizzled

    const int b      = blockIdx.z;
    const int n_tile = blockIdx.x * 128;
    const int m_tile = blockIdx.y * 128;
    const int tid  = threadIdx.x;
    const int lane = tid & 63;
    const int wave = tid >> 6;
    const int wr = wave >> 1, wc = wave & 1;

    // Staging: wave w covers rows w*32..w*32+31 (2 calls x 16 rows).
    // LDS dest = linear lane*16; source slot pre-swizzled: slot ^= (row>>1)&3.
    const int row_in  = lane >> 2;                               // 0..15
    const int srcslot = ((lane & 3) ^ ((lane >> 3) & 3)) * 16;   // bytes

    const int ml0 = wave * 32 + row_in;
    const int ml1 = ml0 + 16;
    const int m0 = m_tile + ml0, m1 = m_tile + ml1;
    const bool mok0 = m0 < MTOT, mok1 = m1 < MTOT;
    const int qy0 = m0 / 33, qx0 = m0 - qy0 * 33;
    const int qy1 = m1 / 33, qx1 = m1 - qy1 * 33;
    const int ng0 = n_tile + ml0;      // B rows always valid (N=2048)
    const int ng1 = n_tile + ml1;

    void* dstA0 = As + wave * 2048;
    void* dstA1 = As + wave * 2048 + 1024;
    void* dstB0 = Bs + wave * 2048;
    void* dstB1 = Bs + wave * 2048 + 1024;

    // Fragment read offsets (fixed per lane): row*64 + swizzled slot*16
    const int fr = lane & 15;
    const int slotr = (((lane >> 4) ^ ((lane >> 1) & 3))) * 16;
    const int aoffs = (wr * 64 + fr) * 64 + slotr;
    const int boffs = (wc * 64 + fr) * 64 + slotr;

    f32x4 acc[4][4] = {};

    for (int d = 0; d < 4; ++d) {
        const int dy = d >> 1, dx = d & 1;
        const int iy0 = qy0 - dy, ix0 = qx0 - dx;
        const int iy1 = qy1 - dy, ix1 = qx1 - dx;
        const bool ok0 = mok0 && ((unsigned)iy0 < 32u) && ((unsigned)ix0 < 32u);
        const bool ok1 = mok1 && ((unsigned)iy1 < 32u) && ((unsigned)ix1 < 32u);
        const size_t aoff0 = ((((size_t)b * 32 + iy0) * 32 + ix0) * 2048) + srcslot;
        const size_t aoff1 = ((((size_t)b * 32 + iy1) * 32 + ix1) * 2048) + srcslot;
        const size_t boff0 = (((((size_t)b * 2 + dx) * 2048 + ng0) * 33 + dy) * 64) + srcslot;
        const size_t boff1 = (((((size_t)b * 2 + dx) * 2048 + ng1) * 33 + dy) * 64) + srcslot;
        const int st0 = ok0 ? 64 : 0;
        const int st1 = ok1 ? 64 : 0;

        for (int t = 0; t < 3; ++t) {
            const char* Ab = (t == 1) ? (const char*)Alo_ : (const char*)Ahi_;
            const char* Bb = (t == 2) ? (const char*)Wlo_ : (const char*)Whi_;
            const char* ap0 = ok0 ? Ab + aoff0 : (const char*)zpad;
            const char* ap1 = ok1 ? Ab + aoff1 : (const char*)zpad;
            const char* bp0 = Bb + boff0;
            const char* bp1 = Bb + boff1;

            for (int s = 0; s < 32; ++s) {
                __syncthreads();               // previous tile fully consumed
                gload16(ap0, dstA0);
                gload16(ap1, dstA1);
                gload16(bp0, dstB0);
                gload16(bp1, dstB1);
                ap0 += st0; ap1 += st1; bp0 += 64; bp1 += 64;
                __syncthreads();               // vmcnt drained -> tile ready
                bf16x8 af[4], bfr[4];
                #pragma unroll
                for (int i = 0; i < 4; ++i)
                    af[i] = *(const bf16x8*)(As + aoffs + i * 1024);
                #pragma unroll
                for (int j = 0; j < 4; ++j)
                    bfr[j] = *(const bf16x8*)(Bs + boffs + j * 1024);
                #pragma unroll
                for (int i = 0; i < 4; ++i)
                    #pragma unroll
                    for (int j = 0; j < 4; ++j)
                        acc[i][j] = __builtin_amdgcn_mfma_f32_16x16x32_bf16(
                            af[i], bfr[j], acc[i][j], 0, 0, 0);
            }
        }
    }

    // Epilogue: C/D layout col=lane&15, row=(lane>>4)*4+reg. Crop [4:260).
    const int r0 = (lane >> 4) * 4;
    #pragma unroll
    for (int i = 0; i < 4; ++i) {
        #pragma unroll
        for (int r = 0; r < 4; ++r) {
            const int m = m_tile + wr * 64 + i * 16 + r0 + r;
            if (m >= MTOT) continue;
            const int qy2 = m / 33, qx2 = m - qy2 * 33;
            #pragma unroll
            for (int j = 0; j < 4; ++j) {
                const int n = n_tile + wc * 64 + j * 16 + fr;
                const int cch = n >> 6, ry = (n >> 3) & 7, rx = n & 7;
                const int y = qy2 * 8 + ry - 4;
                const int x = qx2 * 8 + rx - 4;
                if ((unsigned)y < 256u && (unsigned)x < 256u)
                    out[(((size_t)b * 32 + cch) * 256 + y) * 256 + x] = acc[i][j][r];
            }
        }
    }
}

// ===========================================================================
// Fallback path (round-1 fp32 GEMM) for smaller workspaces.
// ===========================================================================
__global__ void transpose_cos_k(const float* __restrict__ src, float* __restrict__ dst) {
    __shared__ float tile[32][33];
    const int b  = blockIdx.z;
    const int l0 = blockIdx.x * 32;
    const int s0 = blockIdx.y * 32;
    const float* in  = src + (size_t)b * L_DIM * SPA;
    float*       out = dst + (size_t)b * L_DIM * SPA;
    const int tx = threadIdx.x, ty = threadIdx.y;
    #pragma unroll
    for (int i = ty; i < 32; i += 8)
        tile[i][tx] = in[(size_t)(l0 + i) * SPA + s0 + tx];
    __syncthreads();
    #pragma unroll
    for (int i = ty; i < 32; i += 8)
        out[(size_t)(s0 + i) * L_DIM + l0 + tx] = tile[tx][i];
}

__global__ void build_w_k(const float* __restrict__ bsrc, const float* __restrict__ msrc,
                          float* __restrict__ w) {
    const int total = 4 * MTOT * NTOT;
    const int idx = blockIdx.x * 256 + threadIdx.x;
    if (idx >= total) return;
    const int n = idx & (NTOT - 1);
    const int t = idx >> 11;
    const int p = t % MTOT;
    const int b = t / MTOT;
    const int px = p % 33, py = p / 33;
    const int c = n >> 6, ry = (n >> 3) & 7, rx = n & 7;
    int Y = 8 * py + ry - 4;
    int X = 8 * px + rx - 4;
    Y = min(max(Y, 0), 255);
    X = min(max(X, 0), 255);
    const float bv = bsrc[(((size_t)b * 32 + c) * 256 + Y) * 256 + X];
    const float mv = msrc[((size_t)b * 256 + Y) * 256 + X];
    w[idx] = bv * (1.0f - mv);
}

__global__ __launch_bounds__(256) void gemm_deconv_k(const float* __restrict__ cosT,
                                                     const float* __restrict__ W,
                                                     float* __restrict__ out) {
    __shared__ float As_[16][68];
    __shared__ float Bs_[16][64];
    const int b      = blockIdx.z;
    const int n_base = blockIdx.x * 64;
    const int m_base = blockIdx.y * 64;
    const int tid = threadIdx.x;
    const int tx = tid & 15;
    const int ty = tid >> 4;
    float acc[4][4] = {};
    const int arow = m_base + (tid >> 2);
    const int kl   = (tid & 3) * 4;
    const int qy   = arow / 33;
    const int qx   = arow - qy * 33;
    const int brow = tid >> 4;
    const int bcol = (tid & 15) * 4;
    for (int d = 0; d < 4; ++d) {
        const int dy = d >> 1, dx = d & 1;
        const int iy = qy - dy, ix = qx - dx;
        const bool avalid = (arow < MTOT) && ((unsigned)iy < 32u) && ((unsigned)ix < 32u);
        const float* aptr = cosT + (((size_t)b * 32 + iy) * 32 + ix) * L_DIM + kl;
        for (int k0 = 0; k0 < 1024; k0 += 16) {
            float4 av = make_float4(0.f, 0.f, 0.f, 0.f);
            if (avalid) av = *reinterpret_cast<const float4*>(aptr + k0);
            const int kp = k0 + brow;
            const int py = kp >> 5, px = kp & 31;
            const int wrow = (py + dy) * 33 + (px + dx);
            const float4 bv = *reinterpret_cast<const float4*>(
                W + ((size_t)b * MTOT + wrow) * NTOT + n_base + bcol);
            __syncthreads();
            As_[kl + 0][tid >> 2] = av.x;
            As_[kl + 1][tid >> 2] = av.y;
            As_[kl + 2][tid >> 2] = av.z;
            As_[kl + 3][tid >> 2] = av.w;
            *reinterpret_cast<float4*>(&Bs_[brow][bcol]) = bv;
            __syncthreads();
            #pragma unroll
            for (int k = 0; k < 16; ++k) {
                const float4 a  = *reinterpret_cast<const float4*>(&As_[k][ty * 4]);
                const float4 bb = *reinterpret_cast<const float4*>(&Bs_[k][tx * 4]);
                acc[0][0] += a.x * bb.x; acc[0][1] += a.x * bb.y;
                acc[0][2] += a.x * bb.z; acc[0][3] += a.x * bb.w;
                acc[1][0] += a.y * bb.x; acc[1][1] += a.y * bb.y;
                acc[1][2] += a.y * bb.z; acc[1][3] += a.y * bb.w;
                acc[2][0] += a.z * bb.x; acc[2][1] += a.z * bb.y;
                acc[2][2] += a.z * bb.z; acc[2][3] += a.z * bb.w;
                acc[3][0] += a.w * bb.x; acc[3][1] += a.w * bb.y;
                acc[3][2] += a.w * bb.z; acc[3][3] += a.w * bb.w;
            }
        }
    }
    #pragma unroll
    for (int i = 0; i < 4; ++i) {
        const int m = m_base + ty * 4 + i;
        if (m >= MTOT) continue;
        const int qy2 = m / 33, qx2 = m - qy2 * 33;
        #pragma unroll
        for (int j = 0; j < 4; ++j) {
            const int n = n_base + tx * 4 + j;
            const int c = n >> 6, ry = (n >> 3) & 7, rx = n & 7;
            const int y = qy2 * 8 + ry - 4;
            const int x = qx2 * 8 + rx - 4;
            if ((unsigned)y < 256u && (unsigned)x < 256u)
                out[(((size_t)b * 32 + c) * 256 + y) * 256 + x] = acc[i][j];
        }
    }
}

__global__ void naive_deconv_k(const float* __restrict__ cosp, const float* __restrict__ bsrc,
                               const float* __restrict__ msrc, float* __restrict__ out) {
    const int idx = blockIdx.x * 256 + threadIdx.x;
    if (idx >= 4 * 32 * 256 * 256) return;
    const int x = idx & 255, y = (idx >> 8) & 255, c = (idx >> 16) & 31, b = idx >> 21;
    const int oy = y + 4, ox = x + 4;
    const int qy = oy >> 3, ry = oy & 7, qx = ox >> 3, rx = ox & 7;
    float s = 0.f;
    for (int dy = 0; dy < 2; ++dy) {
        for (int dx = 0; dx < 2; ++dx) {
            const int iy = qy - dy, ix = qx - dx;
            if ((unsigned)iy >= 32u || (unsigned)ix >= 32u) continue;
            for (int py = 0; py < 32; ++py) {
                int Y = 8 * (py + dy) + ry - 4;
                Y = min(max(Y, 0), 255);
                for (int px = 0; px < 32; ++px) {
                    int X = 8 * (px + dx) + rx - 4;
                    X = min(max(X, 0), 255);
                    const float cv = cosp[(((size_t)(b * 1024 + py * 32 + px)) * 32 + iy) * 32 + ix];
                    const float bv = bsrc[(((size_t)(b * 32 + c)) * 256 + Y) * 256 + X];
                    const float mv = msrc[((size_t)b * 65536 + (size_t)Y * 256) + X];
                    s += cv * bv * (1.f - mv);
                }
            }
        }
    }
    out[idx] = s;
}

// ---------------------------------------------------------------------------
extern "C" void kernel_launch(void* const* d_in, const int* in_sizes, int n_in,
                              void* d_out, int out_size, void* d_ws, size_t ws_size,
                              hipStream_t stream) {
    const float* cosp = (const float*)d_in[0];
    const float* bp   = (const float*)d_in[1];
    const float* mp   = (const float*)d_in[2];
    float* outp = (float*)d_out;

    const size_t cosT_b = (size_t)4 * 1024 * 1024 * 2;        // 8,388,608 B each
    const size_t wtx_b  = (size_t)4 * 2 * 2048 * 33 * 32 * 2; // 34,603,008 B each
    const size_t need2  = cosT_b * 2 + wtx_b * 2 + 256;       // ~86.0 MB

    const size_t need1 = ((size_t)4 * L_DIM * SPA + (size_t)4 * MTOT * NTOT) * sizeof(float);

    if (ws_size >= need2) {
        char* p = (char*)d_ws;
        unsigned short* cos_hi = (unsigned short*)p; p += cosT_b;
        unsigned short* cos_lo = (unsigned short*)p; p += cosT_b;
        unsigned short* w_hi   = (unsigned short*)p; p += wtx_b;
        unsigned short* w_lo   = (unsigned short*)p; p += wtx_b;
        float* zpad = (float*)p;
        prep_cos_k<<<dim3(32, 32, 4), dim3(32, 8), 0, stream>>>(cosp, cos_hi, cos_lo, zpad);
        const int wtot = 4 * 2 * 2048 * 33 * 32;
        prep_w_k<<<(wtot + 255) / 256, 256, 0, stream>>>(bp, mp, w_hi, w_lo);
        mfma_deconv_k<<<dim3(16, 9, 4), 256, 0, stream>>>(cos_hi, cos_lo, w_hi, w_lo, zpad, outp);
    } else if (ws_size >= need1) {
        float* cosT = (float*)d_ws;
        float* W    = cosT + (size_t)4 * L_DIM * SPA;
        transpose_cos_k<<<dim3(32, 32, 4), dim3(32, 8), 0, stream>>>(cosp, cosT);
        const int wtot = 4 * MTOT * NTOT;
        build_w_k<<<(wtot + 255) / 256, 256, 0, stream>>>(bp, mp, W);
        gemm_deconv_k<<<dim3(32, 18, 4), dim3(256), 0, stream>>>(cosT, W, outp);
    } else {
        const int tot = 4 * 32 * 256 * 256;
        naive_deconv_k<<<(tot + 255) / 256, 256, 0, stream>>>(cosp, bp, mp, outp);
    }
}

// Round 7
// 461.996 us; speedup vs baseline: 2.5711x; 1.0462x over previous
//
#include <hip/hip_runtime.h>
#include <hip/hip_bf16.h>
#include <stdint.h>

#define L_DIM 1024
#define SPA   1024
#define MTOT  1089
#define NTOT  2048

typedef __attribute__((ext_vector_type(8))) short bf16x8;
typedef __attribute__((ext_vector_type(4))) float f32x4;

__device__ __forceinline__ unsigned short f2bf(float x) {
    __hip_bfloat16 h = __float2bfloat16(x);
    return *reinterpret_cast<unsigned short*>(&h);
}
__device__ __forceinline__ float bf2f(unsigned short u) {
    __hip_bfloat16 h;
    *reinterpret_cast<unsigned short*>(&h) = u;
    return __bfloat162float(h);
}

__device__ __forceinline__ void gload16(const void* g, void* l) {
    __builtin_amdgcn_global_load_lds(
        (const __attribute__((address_space(1))) unsigned int*)g,
        (__attribute__((address_space(3))) unsigned int*)l, 16, 0, 0);
}

// ---------------------------------------------------------------------------
// Prep 1: cos (B,L,32,32) -> cosT_hi/lo[b][s=iy*32+ix][l] (bf16, l-contiguous)
// Also zeroes the 256B zpad region (read target for invalid staging rows).
// ---------------------------------------------------------------------------
__global__ void prep_cos_k(const float* __restrict__ src,
                           unsigned short* __restrict__ hi,
                           unsigned short* __restrict__ lo,
                           float* __restrict__ zpad) {
    __shared__ float tile[32][33];
    const int b  = blockIdx.z;
    const int l0 = blockIdx.x * 32;
    const int s0 = blockIdx.y * 32;
    const float* in = src + (size_t)b * L_DIM * SPA;
    const size_t obase = (size_t)b * L_DIM * SPA;
    const int tx = threadIdx.x, ty = threadIdx.y;
    if (blockIdx.x == 0 && blockIdx.y == 0 && blockIdx.z == 0 && ty == 0) {
        zpad[tx] = 0.f; zpad[tx + 32] = 0.f;
    }
    #pragma unroll
    for (int i = ty; i < 32; i += 8)
        tile[i][tx] = in[(size_t)(l0 + i) * SPA + s0 + tx];
    __syncthreads();
    #pragma unroll
    for (int i = ty; i < 32; i += 8) {
        const float x = tile[tx][i];
        const unsigned short h = f2bf(x);
        const size_t o = obase + (size_t)(s0 + i) * L_DIM + l0 + tx;
        hi[o] = h;
        lo[o] = f2bf(x - bf2f(h));
    }
}

// ---------------------------------------------------------------------------
// Prep 2: WTx_hi/lo[b][dx][n][py'][px]  (bf16), px in [0,32) -> 64B rows
//   value = bpad[b,c, 8*py'+ry, 8*(px+dx)+rx] * (1 - mpad[...]) (clamped)
// Grid-encoded indices: grid (33 py, 256 c*8+ry, 8 b*2+dx), block 256 = rx*32+px
// ---------------------------------------------------------------------------
__global__ void prep_w_k(const float* __restrict__ bsrc, const float* __restrict__ msrc,
                         unsigned short* __restrict__ whi, unsigned short* __restrict__ wlo) {
    const int py = blockIdx.x;
    const int c  = blockIdx.y >> 3, ry = blockIdx.y & 7;
    const int b  = blockIdx.z >> 1, dx = blockIdx.z & 1;
    const int px = threadIdx.x & 31, rx = threadIdx.x >> 5;
    int Y = 8 * py + ry - 4;        Y = min(max(Y, 0), 255);
    int X = 8 * (px + dx) + rx - 4; X = min(max(X, 0), 255);
    const float bv = bsrc[(((size_t)b * 32 + c) * 256 + Y) * 256 + X];
    const float mv = msrc[((size_t)b * 256 + Y) * 256 + X];
    const float w = bv * (1.f - mv);
    const unsigned short h = f2bf(w);
    const int n = c * 64 + ry * 8 + rx;
    const size_t o = ((((size_t)b * 2 + dx) * 2048 + n) * 33 + py) * 32 + px;
    whi[o] = h;
    wlo[o] = f2bf(w - bf2f(h));
}

// ---------------------------------------------------------------------------
// MFMA GEMM, deep-pipelined: flat 384-step loop (12 phases x 32 K-steps),
// 3-slot LDS ring, always-stage 2 tiles ahead, counted s_waitcnt vmcnt(4),
// raw s_barrier, setprio around the 16-MFMA cluster, XCD-chunked swizzle.
// ---------------------------------------------------------------------------
__global__ __launch_bounds__(256, 3) void mfma_deconv_k(
    const unsigned short* __restrict__ Ahi_, const unsigned short* __restrict__ Alo_,
    const unsigned short* __restrict__ Whi_, const unsigned short* __restrict__ Wlo_,
    const float* __restrict__ zpad, float* __restrict__ out)
{
    __shared__ int lds_i[12288];           // 48 KB: 3 slots x (8KB A + 8KB B)
    char* lds = (char*)lds_i;

    // XCD-chunked bijective swizzle: grid 576 = 8 XCDs x 72 blocks.
    const int orig = blockIdx.x;
    const int wg   = (orig & 7) * 72 + (orig >> 3);
    const int bx   = wg & 15;            // n-tile [0,16)
    const int rem  = wg >> 4;            // [0,36)
    const int by   = rem % 9;            // m-tile [0,9)
    const int b    = rem / 9;            // batch [0,4)
    const int n_tile = bx * 128;
    const int m_tile = by * 128;

    const int tid  = threadIdx.x;
    const int lane = tid & 63;
    const int wave = tid >> 6;
    const int wr = wave >> 1, wc = wave & 1;

    // Staging geometry (unchanged from verified round-3 kernel):
    const int row_in  = lane >> 2;                               // 0..15
    const int srcslot = ((lane & 3) ^ ((lane >> 3) & 3)) * 16;   // pre-swizzled src slot
    const int ml0 = wave * 32 + row_in;
    const int ml1 = ml0 + 16;
    const int m0 = m_tile + ml0, m1 = m_tile + ml1;
    const bool mok0 = m0 < MTOT, mok1 = m1 < MTOT;
    const int qy0 = m0 / 33, qx0 = m0 - qy0 * 33;
    const int qy1 = m1 / 33, qx1 = m1 - qy1 * 33;
    const int ng0 = n_tile + ml0;
    const int ng1 = n_tile + ml1;

    // LDS dest offsets within a ring slot (linear, lane*16 via gload semantics)
    const int dA0 = wave * 2048;
    const int dA1 = wave * 2048 + 1024;
    const int dB0 = 8192 + wave * 2048;
    const int dB1 = 8192 + wave * 2048 + 1024;

    // Fragment read offsets (swizzle-matched)
    const int fr = lane & 15;
    const int slotr = ((lane >> 4) ^ ((lane >> 1) & 3)) * 16;
    const int aoffs = (wr * 64 + fr) * 64 + slotr;
    const int boffs = 8192 + (wc * 64 + fr) * 64 + slotr;

    f32x4 acc[4][4] = {};

    // Stage-stream state (leads compute by 2 tiles)
    const char *ap0, *ap1, *bp0, *bp1;
    int sa0, sa1, sbs;
    int sw = 0, st_ = 0, sd = 0;

    auto phase_setup = [&](int d, int t) {
        if (d >= 4) {   // past last real tile: dummy stages from zpad
            ap0 = ap1 = bp0 = bp1 = (const char*)zpad;
            sa0 = sa1 = sbs = 0;
            return;
        }
        const int dy = d >> 1, dxx = d & 1;
        const int iy0 = qy0 - dy, ix0 = qx0 - dxx;
        const int iy1 = qy1 - dy, ix1 = qx1 - dxx;
        const bool ok0 = mok0 && ((unsigned)iy0 < 32u) && ((unsigned)ix0 < 32u);
        const bool ok1 = mok1 && ((unsigned)iy1 < 32u) && ((unsigned)ix1 < 32u);
        const char* Ab = (t == 1) ? (const char*)Alo_ : (const char*)Ahi_;
        const char* Bb = (t == 2) ? (const char*)Wlo_ : (const char*)Whi_;
        const size_t aoff0 = ((((size_t)b * 32 + iy0) * 32 + ix0) * 2048) + srcslot;
        const size_t aoff1 = ((((size_t)b * 32 + iy1) * 32 + ix1) * 2048) + srcslot;
        const size_t boff0 = (((((size_t)b * 2 + dxx) * 2048 + ng0) * 33 + dy) * 64) + srcslot;
        const size_t boff1 = (((((size_t)b * 2 + dxx) * 2048 + ng1) * 33 + dy) * 64) + srcslot;
        ap0 = ok0 ? Ab + aoff0 : (const char*)zpad;  sa0 = ok0 ? 64 : 0;
        ap1 = ok1 ? Ab + aoff1 : (const char*)zpad;  sa1 = ok1 ? 64 : 0;
        bp0 = Bb + boff0;  bp1 = Bb + boff1;  sbs = 64;
    };

    auto issue = [&](int slot) {
        char* sb_ = lds + slot * 16384;
        gload16(ap0, sb_ + dA0);
        gload16(ap1, sb_ + dA1);
        gload16(bp0, sb_ + dB0);
        gload16(bp1, sb_ + dB1);
        ap0 += sa0; ap1 += sa1; bp0 += sbs; bp1 += sbs;
        if (++sw == 32) {            // uniform branch, every 32 steps
            sw = 0;
            if (++st_ == 3) { st_ = 0; ++sd; }
            phase_setup(sd, st_);
        }
    };

    phase_setup(0, 0);
    issue(0);                         // tile 0 -> slot 0 (4 loads/wave)
    issue(1);                         // tile 1 -> slot 1 (8 outstanding)
    asm volatile("s_waitcnt vmcnt(4)" ::: "memory");   // tile 0 landed
    __builtin_amdgcn_s_barrier();

    int cslot = 0, sslot = 2;
    for (int s = 0; s < 384; ++s) {
        issue(sslot);                 // tile s+2 in flight (8 outstanding)
        const char* cb = lds + cslot * 16384;
        bf16x8 af[4], bfr[4];
        #pragma unroll
        for (int i = 0; i < 4; ++i) af[i]  = *(const bf16x8*)(cb + aoffs + i * 1024);
        #pragma unroll
        for (int j = 0; j < 4; ++j) bfr[j] = *(const bf16x8*)(cb + boffs + j * 1024);
        __builtin_amdgcn_s_setprio(1);
        #pragma unroll
        for (int i = 0; i < 4; ++i)
            #pragma unroll
            for (int j = 0; j < 4; ++j)
                acc[i][j] = __builtin_amdgcn_mfma_f32_16x16x32_bf16(
                    af[i], bfr[j], acc[i][j], 0, 0, 0);
        __builtin_amdgcn_s_setprio(0);
        asm volatile("s_waitcnt vmcnt(4)" ::: "memory");   // tile s+1 landed
        __builtin_amdgcn_s_barrier();
        cslot = (cslot == 2) ? 0 : cslot + 1;
        sslot = (sslot == 2) ? 0 : sslot + 1;
    }

    // Epilogue: C/D layout col=lane&15, row=(lane>>4)*4+reg. Crop [4:260).
    const int r0 = (lane >> 4) * 4;
    #pragma unroll
    for (int i = 0; i < 4; ++i) {
        #pragma unroll
        for (int r = 0; r < 4; ++r) {
            const int m = m_tile + wr * 64 + i * 16 + r0 + r;
            if (m >= MTOT) continue;
            const int qy2 = m / 33, qx2 = m - qy2 * 33;
            #pragma unroll
            for (int j = 0; j < 4; ++j) {
                const int n = n_tile + wc * 64 + j * 16 + fr;
                const int cch = n >> 6, ry = (n >> 3) & 7, rx = n & 7;
                const int y = qy2 * 8 + ry - 4;
                const int x = qx2 * 8 + rx - 4;
                if ((unsigned)y < 256u && (unsigned)x < 256u)
                    out[(((size_t)b * 32 + cch) * 256 + y) * 256 + x] = acc[i][j][r];
            }
        }
    }
}

// ===========================================================================
// Fallback path (fp32 GEMM) for smaller workspaces.
// ===========================================================================
__global__ void transpose_cos_k(const float* __restrict__ src, float* __restrict__ dst) {
    __shared__ float tile[32][33];
    const int b  = blockIdx.z;
    const int l0 = blockIdx.x * 32;
    const int s0 = blockIdx.y * 32;
    const float* in  = src + (size_t)b * L_DIM * SPA;
    float*       out = dst + (size_t)b * L_DIM * SPA;
    const int tx = threadIdx.x, ty = threadIdx.y;
    #pragma unroll
    for (int i = ty; i < 32; i += 8)
        tile[i][tx] = in[(size_t)(l0 + i) * SPA + s0 + tx];
    __syncthreads();
    #pragma unroll
    for (int i = ty; i < 32; i += 8)
        out[(size_t)(s0 + i) * L_DIM + l0 + tx] = tile[tx][i];
}

__global__ void build_w_k(const float* __restrict__ bsrc, const float* __restrict__ msrc,
                          float* __restrict__ w) {
    const int total = 4 * MTOT * NTOT;
    const int idx = blockIdx.x * 256 + threadIdx.x;
    if (idx >= total) return;
    const int n = idx & (NTOT - 1);
    const int t = idx >> 11;
    const int p = t % MTOT;
    const int b = t / MTOT;
    const int px = p % 33, py = p / 33;
    const int c = n >> 6, ry = (n >> 3) & 7, rx = n & 7;
    int Y = 8 * py + ry - 4;
    int X = 8 * px + rx - 4;
    Y = min(max(Y, 0), 255);
    X = min(max(X, 0), 255);
    const float bv = bsrc[(((size_t)b * 32 + c) * 256 + Y) * 256 + X];
    const float mv = msrc[((size_t)b * 256 + Y) * 256 + X];
    w[idx] = bv * (1.0f - mv);
}

__global__ __launch_bounds__(256) void gemm_deconv_k(const float* __restrict__ cosT,
                                                     const float* __restrict__ W,
                                                     float* __restrict__ out) {
    __shared__ float As_[16][68];
    __shared__ float Bs_[16][64];
    const int b      = blockIdx.z;
    const int n_base = blockIdx.x * 64;
    const int m_base = blockIdx.y * 64;
    const int tid = threadIdx.x;
    const int tx = tid & 15;
    const int ty = tid >> 4;
    float acc[4][4] = {};
    const int arow = m_base + (tid >> 2);
    const int kl   = (tid & 3) * 4;
    const int qy   = arow / 33;
    const int qx   = arow - qy * 33;
    const int brow = tid >> 4;
    const int bcol = (tid & 15) * 4;
    for (int d = 0; d < 4; ++d) {
        const int dy = d >> 1, dx = d & 1;
        const int iy = qy - dy, ix = qx - dx;
        const bool avalid = (arow < MTOT) && ((unsigned)iy < 32u) && ((unsigned)ix < 32u);
        const float* aptr = cosT + (((size_t)b * 32 + iy) * 32 + ix) * L_DIM + kl;
        for (int k0 = 0; k0 < 1024; k0 += 16) {
            float4 av = make_float4(0.f, 0.f, 0.f, 0.f);
            if (avalid) av = *reinterpret_cast<const float4*>(aptr + k0);
            const int kp = k0 + brow;
            const int py = kp >> 5, px = kp & 31;
            const int wrow = (py + dy) * 33 + (px + dx);
            const float4 bv = *reinterpret_cast<const float4*>(
                W + ((size_t)b * MTOT + wrow) * NTOT + n_base + bcol);
            __syncthreads();
            As_[kl + 0][tid >> 2] = av.x;
            As_[kl + 1][tid >> 2] = av.y;
            As_[kl + 2][tid >> 2] = av.z;
            As_[kl + 3][tid >> 2] = av.w;
            *reinterpret_cast<float4*>(&Bs_[brow][bcol]) = bv;
            __syncthreads();
            #pragma unroll
            for (int k = 0; k < 16; ++k) {
                const float4 a  = *reinterpret_cast<const float4*>(&As_[k][ty * 4]);
                const float4 bb = *reinterpret_cast<const float4*>(&Bs_[k][tx * 4]);
                acc[0][0] += a.x * bb.x; acc[0][1] += a.x * bb.y;
                acc[0][2] += a.x * bb.z; acc[0][3] += a.x * bb.w;
                acc[1][0] += a.y * bb.x; acc[1][1] += a.y * bb.y;
                acc[1][2] += a.y * bb.z; acc[1][3] += a.y * bb.w;
                acc[2][0] += a.z * bb.x; acc[2][1] += a.z * bb.y;
                acc[2][2] += a.z * bb.z; acc[2][3] += a.z * bb.w;
                acc[3][0] += a.w * bb.x; acc[3][1] += a.w * bb.y;
                acc[3][2] += a.w * bb.z; acc[3][3] += a.w * bb.w;
            }
        }
    }
    #pragma unroll
    for (int i = 0; i < 4; ++i) {
        const int m = m_base + ty * 4 + i;
        if (m >= MTOT) continue;
        const int qy2 = m / 33, qx2 = m - qy2 * 33;
        #pragma unroll
        for (int j = 0; j < 4; ++j) {
            const int n = n_base + tx * 4 + j;
            const int c = n >> 6, ry = (n >> 3) & 7, rx = n & 7;
            const int y = qy2 * 8 + ry - 4;
            const int x = qx2 * 8 + rx - 4;
            if ((unsigned)y < 256u && (unsigned)x < 256u)
                out[(((size_t)b * 32 + c) * 256 + y) * 256 + x] = acc[i][j];
        }
    }
}

__global__ void naive_deconv_k(const float* __restrict__ cosp, const float* __restrict__ bsrc,
                               const float* __restrict__ msrc, float* __restrict__ out) {
    const int idx = blockIdx.x * 256 + threadIdx.x;
    if (idx >= 4 * 32 * 256 * 256) return;
    const int x = idx & 255, y = (idx >> 8) & 255, c = (idx >> 16) & 31, b = idx >> 21;
    const int oy = y + 4, ox = x + 4;
    const int qy = oy >> 3, ry = oy & 7, qx = ox >> 3, rx = ox & 7;
    float s = 0.f;
    for (int dy = 0; dy < 2; ++dy) {
        for (int dx = 0; dx < 2; ++dx) {
            const int iy = qy - dy, ix = qx - dx;
            if ((unsigned)iy >= 32u || (unsigned)ix >= 32u) continue;
            for (int py = 0; py < 32; ++py) {
                int Y = 8 * (py + dy) + ry - 4;
                Y = min(max(Y, 0), 255);
                for (int px = 0; px < 32; ++px) {
                    int X = 8 * (px + dx) + rx - 4;
                    X = min(max(X, 0), 255);
                    const float cv = cosp[(((size_t)(b * 1024 + py * 32 + px)) * 32 + iy) * 32 + ix];
                    const float bv = bsrc[(((size_t)(b * 32 + c)) * 256 + Y) * 256 + X];
                    const float mv = msrc[((size_t)b * 65536 + (size_t)Y * 256) + X];
                    s += cv * bv * (1.f - mv);
                }
            }
        }
    }
    out[idx] = s;
}

// ---------------------------------------------------------------------------
extern "C" void kernel_launch(void* const* d_in, const int* in_sizes, int n_in,
                              void* d_out, int out_size, void* d_ws, size_t ws_size,
                              hipStream_t stream) {
    const float* cosp = (const float*)d_in[0];
    const float* bp   = (const float*)d_in[1];
    const float* mp   = (const float*)d_in[2];
    float* outp = (float*)d_out;

    const size_t cosT_b = (size_t)4 * 1024 * 1024 * 2;        // 8,388,608 B each
    const size_t wtx_b  = (size_t)4 * 2 * 2048 * 33 * 32 * 2; // 34,603,008 B each
    const size_t need2  = cosT_b * 2 + wtx_b * 2 + 256;       // ~86.0 MB

    const size_t need1 = ((size_t)4 * L_DIM * SPA + (size_t)4 * MTOT * NTOT) * sizeof(float);

    if (ws_size >= need2) {
        char* p = (char*)d_ws;
        unsigned short* cos_hi = (unsigned short*)p; p += cosT_b;
        unsigned short* cos_lo = (unsigned short*)p; p += cosT_b;
        unsigned short* w_hi   = (unsigned short*)p; p += wtx_b;
        unsigned short* w_lo   = (unsigned short*)p; p += wtx_b;
        float* zpad = (float*)p;
        prep_cos_k<<<dim3(32, 32, 4), dim3(32, 8), 0, stream>>>(cosp, cos_hi, cos_lo, zpad);
        prep_w_k<<<dim3(33, 256, 8), 256, 0, stream>>>(bp, mp, w_hi, w_lo);
        mfma_deconv_k<<<576, 256, 0, stream>>>(cos_hi, cos_lo, w_hi, w_lo, zpad, outp);
    } else if (ws_size >= need1) {
        float* cosT = (float*)d_ws;
        float* W    = cosT + (size_t)4 * L_DIM * SPA;
        transpose_cos_k<<<dim3(32, 32, 4), dim3(32, 8), 0, stream>>>(cosp, cosT);
        const int wtot = 4 * MTOT * NTOT;
        build_w_k<<<(wtot + 255) / 256, 256, 0, stream>>>(bp, mp, W);
        gemm_deconv_k<<<dim3(32, 18, 4), dim3(256), 0, stream>>>(cosT, W, outp);
    } else {
        const int tot = 4 * 32 * 256 * 256;
        naive_deconv_k<<<(tot + 255) / 256, 256, 0, stream>>>(cosp, bp, mp, outp);
    }
}

// Round 8
// 253.678 us; speedup vs baseline: 4.6826x; 1.8212x over previous
//
#include <hip/hip_runtime.h>
#include <hip/hip_bf16.h>
#include <stdint.h>

#define L_DIM 1024
#define SPA   1024
#define MTOT  1089   // 33*33 output macro grid
#define NTOT  2048   // 32c * 8ry * 8rx
#define KU    1120   // u-dim padded (1089 -> 35*32)
#define MPAD  1152   // M padded to 9*128
#define NSTEP 105    // 3 terms * 35 K-chunks

typedef __attribute__((ext_vector_type(8))) short bf16x8;
typedef __attribute__((ext_vector_type(4))) float f32x4;

__device__ __forceinline__ unsigned short f2bf(float x) {
    __hip_bfloat16 h = __float2bfloat16(x);
    return *reinterpret_cast<unsigned short*>(&h);
}
__device__ __forceinline__ float bf2f(unsigned short u) {
    __hip_bfloat16 h;
    *reinterpret_cast<unsigned short*>(&h) = u;
    return __bfloat162float(h);
}

__device__ __forceinline__ void gload16(const void* g, void* l) {
    __builtin_amdgcn_global_load_lds(
        (const __attribute__((address_space(1))) unsigned int*)g,
        (__attribute__((address_space(3))) unsigned int*)l, 16, 0, 0);
}

// ---------------------------------------------------------------------------
// Stage 1: transpose cos (B,L=p,32,32) -> cosT f32 [b][s=iy*32+ix][p]
// ---------------------------------------------------------------------------
__global__ void transpose_cos_k(const float* __restrict__ src, float* __restrict__ dst) {
    __shared__ float tile[32][33];
    const int b  = blockIdx.z;
    const int l0 = blockIdx.x * 32;
    const int s0 = blockIdx.y * 32;
    const float* in  = src + (size_t)b * L_DIM * SPA;
    float*       out = dst + (size_t)b * L_DIM * SPA;
    const int tx = threadIdx.x, ty = threadIdx.y;
    #pragma unroll
    for (int i = ty; i < 32; i += 8)
        tile[i][tx] = in[(size_t)(l0 + i) * SPA + s0 + tx];
    __syncthreads();
    #pragma unroll
    for (int i = ty; i < 32; i += 8)
        out[(size_t)(s0 + i) * L_DIM + l0 + tx] = tile[tx][i];
}

// ---------------------------------------------------------------------------
// Stage 2: C'T[b][q][u] = sum_d cosT[b][q-d][u-d] (masked), split hi/lo bf16.
// Rows q in [1089,1152) and cols u>=1089 are zero (u>=1089 is zero naturally:
// uy=33 fails both d-masks). Grid (q=1152, b=4), 256 threads.
// ---------------------------------------------------------------------------
__global__ void build_ct_k(const float* __restrict__ cosT,
                           unsigned short* __restrict__ chi,
                           unsigned short* __restrict__ clo) {
    const int q = blockIdx.x;
    const int b = blockIdx.y;
    const size_t orow = ((size_t)b * MPAD + q) * KU;
    if (q >= MTOT) {
        for (int u = threadIdx.x; u < KU; u += 256) { chi[orow+u] = 0; clo[orow+u] = 0; }
        return;
    }
    const int qy = q / 33, qx = q - qy * 33;
    // per-d source row base (or invalid)
    const float* rp[4];
    bool rv[4];
    #pragma unroll
    for (int d = 0; d < 4; ++d) {
        const int dy = d >> 1, dx = d & 1;
        const int sy = qy - dy, sx = qx - dx;
        rv[d] = ((unsigned)sy < 32u) && ((unsigned)sx < 32u);
        rp[d] = cosT + (((size_t)b * 1024) + sy * 32 + sx) * 1024;
    }
    for (int u = threadIdx.x; u < KU; u += 256) {
        const int uy = u / 33, ux = u - uy * 33;
        float v = 0.f;
        #pragma unroll
        for (int d = 0; d < 4; ++d) {
            const int dy = d >> 1, dx = d & 1;
            const int py = uy - dy, px = ux - dx;
            if (rv[d] && (unsigned)py < 32u && (unsigned)px < 32u)
                v += rp[d][py * 32 + px];
        }
        const unsigned short h = f2bf(v);
        chi[orow + u] = h;
        clo[orow + u] = f2bf(v - bf2f(h));
    }
}

// ---------------------------------------------------------------------------
// Stage 3: W[b][n][u] hi/lo bf16.  n = c*64+ry*8+rx, u=(uy,ux) in 33x33.
//   W = bpad[b,c, 8uy+ry, 8ux+rx] * (1 - mpad[...]) (replicate clamp).
// u >= 1089 zeroed. Grid (5, n=2048, b=4), 256 threads (u = bx*256+tid).
// ---------------------------------------------------------------------------
__global__ void prep_w2_k(const float* __restrict__ bsrc, const float* __restrict__ msrc,
                          unsigned short* __restrict__ whi, unsigned short* __restrict__ wlo) {
    const int u = blockIdx.x * 256 + threadIdx.x;
    if (u >= KU) return;
    const int n = blockIdx.y;
    const int b = blockIdx.z;
    const size_t o = ((size_t)b * NTOT + n) * KU + u;
    if (u >= MTOT) { whi[o] = 0; wlo[o] = 0; return; }
    const int uy = u / 33, ux = u - uy * 33;
    const int c = n >> 6, ry = (n >> 3) & 7, rx = n & 7;
    int Y = 8 * uy + ry - 4; Y = min(max(Y, 0), 255);
    int X = 8 * ux + rx - 4; X = min(max(X, 0), 255);
    const float bv = bsrc[(((size_t)b * 32 + c) * 256 + Y) * 256 + X];
    const float mv = msrc[((size_t)b * 256 + Y) * 256 + X];
    const float w = bv * (1.f - mv);
    const unsigned short h = f2bf(w);
    whi[o] = h;
    wlo[o] = f2bf(w - bf2f(h));
}

// ---------------------------------------------------------------------------
// Stage 4: MFMA GEMM, K=1120 x 3 split-terms = 105 flat steps.
// out[m][n] = sum_u A[m][u] * W[n][u]; terms (hi,hi),(lo,hi),(hi,lo).
// 128x128 tile, BK=32, 4 waves, 3-slot LDS ring, stage-2-ahead, vmcnt(4),
// raw s_barrier, setprio, XCD-chunked swizzle. No validity logic (zero-pad).
// ---------------------------------------------------------------------------
__global__ __launch_bounds__(256, 3) void mfma_deconv2_k(
    const unsigned short* __restrict__ Ahi_, const unsigned short* __restrict__ Alo_,
    const unsigned short* __restrict__ Whi_, const unsigned short* __restrict__ Wlo_,
    float* __restrict__ out)
{
    __shared__ int lds_i[12288];           // 48 KB: 3 slots x (8KB A + 8KB B)
    char* lds = (char*)lds_i;

    // XCD-chunked bijective swizzle: grid 576 = 8 XCDs x 72 blocks.
    const int orig = blockIdx.x;
    const int wg   = (orig & 7) * 72 + (orig >> 3);
    const int bx   = wg & 15;            // n-tile [0,16)
    const int rem  = wg >> 4;            // [0,36)
    const int by   = rem % 9;            // m-tile [0,9)
    const int b    = rem / 9;            // batch [0,4)
    const int n_tile = bx * 128;
    const int m_tile = by * 128;

    const int tid  = threadIdx.x;
    const int lane = tid & 63;
    const int wave = tid >> 6;
    const int wr = wave >> 1, wc = wave & 1;

    // Staging geometry (verified r3/r7): wave w rows w*32..w*32+31, 2 gloads x 16 rows.
    const int row_in  = lane >> 2;                               // 0..15
    const int srcslot = ((lane & 3) ^ ((lane >> 3) & 3)) * 16;   // pre-swizzled src slot
    const int ml0 = wave * 32 + row_in;
    const int ml1 = ml0 + 16;

    // Per-term row byte-offsets (row stride = KU*2 = 2240 B)
    const size_t aoff0 = ((size_t)(b * MPAD + m_tile + ml0)) * (KU * 2) + srcslot;
    const size_t aoff1 = ((size_t)(b * MPAD + m_tile + ml1)) * (KU * 2) + srcslot;
    const size_t boff0 = ((size_t)(b * NTOT + n_tile + ml0)) * (KU * 2) + srcslot;
    const size_t boff1 = ((size_t)(b * NTOT + n_tile + ml1)) * (KU * 2) + srcslot;

    // LDS dest offsets within a ring slot (lane-linear via gload semantics)
    const int dA0 = wave * 2048;
    const int dA1 = wave * 2048 + 1024;
    const int dB0 = 8192 + wave * 2048;
    const int dB1 = 8192 + wave * 2048 + 1024;

    // Fragment read offsets (swizzle-matched, verified)
    const int fr = lane & 15;
    const int slotr = ((lane >> 4) ^ ((lane >> 1) & 3)) * 16;
    const int aoffs = (wr * 64 + fr) * 64 + slotr;
    const int boffs = 8192 + (wc * 64 + fr) * 64 + slotr;

    f32x4 acc[4][4] = {};

    // Stage-stream state (leads compute by 2 tiles)
    const char *ap0, *ap1, *bp0, *bp1;
    int sw = 0, tt = 0;

    auto term_setup = [&](int t) {
        const char* Ab = (t == 1) ? (const char*)Alo_ : (const char*)Ahi_;
        const char* Bb = (t >= 2) ? (const char*)Wlo_ : (const char*)Whi_;
        ap0 = Ab + aoff0; ap1 = Ab + aoff1;
        bp0 = Bb + boff0; bp1 = Bb + boff1;
    };

    auto issue = [&](int slot) {
        char* sb_ = lds + slot * 16384;
        gload16(ap0, sb_ + dA0);
        gload16(ap1, sb_ + dA1);
        gload16(bp0, sb_ + dB0);
        gload16(bp1, sb_ + dB1);
        ap0 += 64; ap1 += 64; bp0 += 64; bp1 += 64;
        if (++sw == 35) {            // uniform branch at term boundary
            sw = 0;
            ++tt;                    // tt>=3: dummy re-stage of term-2 head (in-bounds, never read)
            term_setup(tt);
        }
    };

    term_setup(0);
    issue(0);                         // tile 0 -> slot 0 (4 loads/wave)
    issue(1);                         // tile 1 -> slot 1 (8 outstanding)
    asm volatile("s_waitcnt vmcnt(4)" ::: "memory");   // tile 0 landed
    __builtin_amdgcn_s_barrier();

    int cslot = 0, sslot = 2;
    for (int s = 0; s < NSTEP; ++s) {
        issue(sslot);                 // tile s+2 in flight (8 outstanding)
        const char* cb = lds + cslot * 16384;
        bf16x8 af[4], bfr[4];
        #pragma unroll
        for (int i = 0; i < 4; ++i) af[i]  = *(const bf16x8*)(cb + aoffs + i * 1024);
        #pragma unroll
        for (int j = 0; j < 4; ++j) bfr[j] = *(const bf16x8*)(cb + boffs + j * 1024);
        __builtin_amdgcn_s_setprio(1);
        #pragma unroll
        for (int i = 0; i < 4; ++i)
            #pragma unroll
            for (int j = 0; j < 4; ++j)
                acc[i][j] = __builtin_amdgcn_mfma_f32_16x16x32_bf16(
                    af[i], bfr[j], acc[i][j], 0, 0, 0);
        __builtin_amdgcn_s_setprio(0);
        asm volatile("s_waitcnt vmcnt(4)" ::: "memory");   // tile s+1 landed
        __builtin_amdgcn_s_barrier();
        cslot = (cslot == 2) ? 0 : cslot + 1;
        sslot = (sslot == 2) ? 0 : sslot + 1;
    }

    // Epilogue: C/D layout col=lane&15, row=(lane>>4)*4+reg. Crop [4:260).
    const int r0 = (lane >> 4) * 4;
    #pragma unroll
    for (int i = 0; i < 4; ++i) {
        #pragma unroll
        for (int r = 0; r < 4; ++r) {
            const int m = m_tile + wr * 64 + i * 16 + r0 + r;
            if (m >= MTOT) continue;
            const int qy2 = m / 33, qx2 = m - qy2 * 33;
            #pragma unroll
            for (int j = 0; j < 4; ++j) {
                const int n = n_tile + wc * 64 + j * 16 + fr;
                const int cch = n >> 6, ry = (n >> 3) & 7, rx = n & 7;
                const int y = qy2 * 8 + ry - 4;
                const int x = qx2 * 8 + rx - 4;
                if ((unsigned)y < 256u && (unsigned)x < 256u)
                    out[(((size_t)b * 32 + cch) * 256 + y) * 256 + x] = acc[i][j][r];
            }
        }
    }
}

// ===========================================================================
// Fallback path (fp32 GEMM, verified round 1) for smaller workspaces.
// ===========================================================================
__global__ void build_w_k(const float* __restrict__ bsrc, const float* __restrict__ msrc,
                          float* __restrict__ w) {
    const int total = 4 * MTOT * NTOT;
    const int idx = blockIdx.x * 256 + threadIdx.x;
    if (idx >= total) return;
    const int n = idx & (NTOT - 1);
    const int t = idx >> 11;
    const int p = t % MTOT;
    const int b = t / MTOT;
    const int px = p % 33, py = p / 33;
    const int c = n >> 6, ry = (n >> 3) & 7, rx = n & 7;
    int Y = 8 * py + ry - 4;
    int X = 8 * px + rx - 4;
    Y = min(max(Y, 0), 255);
    X = min(max(X, 0), 255);
    const float bv = bsrc[(((size_t)b * 32 + c) * 256 + Y) * 256 + X];
    const float mv = msrc[((size_t)b * 256 + Y) * 256 + X];
    w[idx] = bv * (1.0f - mv);
}

__global__ __launch_bounds__(256) void gemm_deconv_k(const float* __restrict__ cosT,
                                                     const float* __restrict__ W,
                                                     float* __restrict__ out) {
    __shared__ float As_[16][68];
    __shared__ float Bs_[16][64];
    const int b      = blockIdx.z;
    const int n_base = blockIdx.x * 64;
    const int m_base = blockIdx.y * 64;
    const int tid = threadIdx.x;
    const int tx = tid & 15;
    const int ty = tid >> 4;
    float acc[4][4] = {};
    const int arow = m_base + (tid >> 2);
    const int kl   = (tid & 3) * 4;
    const int qy   = arow / 33;
    const int qx   = arow - qy * 33;
    const int brow = tid >> 4;
    const int bcol = (tid & 15) * 4;
    for (int d = 0; d < 4; ++d) {
        const int dy = d >> 1, dx = d & 1;
        const int iy = qy - dy, ix = qx - dx;
        const bool avalid = (arow < MTOT) && ((unsigned)iy < 32u) && ((unsigned)ix < 32u);
        const float* aptr = cosT + (((size_t)b * 32 + iy) * 32 + ix) * L_DIM + kl;
        for (int k0 = 0; k0 < 1024; k0 += 16) {
            float4 av = make_float4(0.f, 0.f, 0.f, 0.f);
            if (avalid) av = *reinterpret_cast<const float4*>(aptr + k0);
            const int kp = k0 + brow;
            const int py = kp >> 5, px = kp & 31;
            const int wrow = (py + dy) * 33 + (px + dx);
            const float4 bv = *reinterpret_cast<const float4*>(
                W + ((size_t)b * MTOT + wrow) * NTOT + n_base + bcol);
            __syncthreads();
            As_[kl + 0][tid >> 2] = av.x;
            As_[kl + 1][tid >> 2] = av.y;
            As_[kl + 2][tid >> 2] = av.z;
            As_[kl + 3][tid >> 2] = av.w;
            *reinterpret_cast<float4*>(&Bs_[brow][bcol]) = bv;
            __syncthreads();
            #pragma unroll
            for (int k = 0; k < 16; ++k) {
                const float4 a  = *reinterpret_cast<const float4*>(&As_[k][ty * 4]);
                const float4 bb = *reinterpret_cast<const float4*>(&Bs_[k][tx * 4]);
                acc[0][0] += a.x * bb.x; acc[0][1] += a.x * bb.y;
                acc[0][2] += a.x * bb.z; acc[0][3] += a.x * bb.w;
                acc[1][0] += a.y * bb.x; acc[1][1] += a.y * bb.y;
                acc[1][2] += a.y * bb.z; acc[1][3] += a.y * bb.w;
                acc[2][0] += a.z * bb.x; acc[2][1] += a.z * bb.y;
                acc[2][2] += a.z * bb.z; acc[2][3] += a.z * bb.w;
                acc[3][0] += a.w * bb.x; acc[3][1] += a.w * bb.y;
                acc[3][2] += a.w * bb.z; acc[3][3] += a.w * bb.w;
            }
        }
    }
    #pragma unroll
    for (int i = 0; i < 4; ++i) {
        const int m = m_base + ty * 4 + i;
        if (m >= MTOT) continue;
        const int qy2 = m / 33, qx2 = m - qy2 * 33;
        #pragma unroll
        for (int j = 0; j < 4; ++j) {
            const int n = n_base + tx * 4 + j;
            const int c = n >> 6, ry = (n >> 3) & 7, rx = n & 7;
            const int y = qy2 * 8 + ry - 4;
            const int x = qx2 * 8 + rx - 4;
            if ((unsigned)y < 256u && (unsigned)x < 256u)
                out[(((size_t)b * 32 + c) * 256 + y) * 256 + x] = acc[i][j];
        }
    }
}

__global__ void naive_deconv_k(const float* __restrict__ cosp, const float* __restrict__ bsrc,
                               const float* __restrict__ msrc, float* __restrict__ out) {
    const int idx = blockIdx.x * 256 + threadIdx.x;
    if (idx >= 4 * 32 * 256 * 256) return;
    const int x = idx & 255, y = (idx >> 8) & 255, c = (idx >> 16) & 31, b = idx >> 21;
    const int oy = y + 4, ox = x + 4;
    const int qy = oy >> 3, ry = oy & 7, qx = ox >> 3, rx = ox & 7;
    float s = 0.f;
    for (int dy = 0; dy < 2; ++dy) {
        for (int dx = 0; dx < 2; ++dx) {
            const int iy = qy - dy, ix = qx - dx;
            if ((unsigned)iy >= 32u || (unsigned)ix >= 32u) continue;
            for (int py = 0; py < 32; ++py) {
                int Y = 8 * (py + dy) + ry - 4;
                Y = min(max(Y, 0), 255);
                for (int px = 0; px < 32; ++px) {
                    int X = 8 * (px + dx) + rx - 4;
                    X = min(max(X, 0), 255);
                    const float cv = cosp[(((size_t)(b * 1024 + py * 32 + px)) * 32 + iy) * 32 + ix];
                    const float bv = bsrc[(((size_t)(b * 32 + c)) * 256 + Y) * 256 + X];
                    const float mv = msrc[((size_t)b * 65536 + (size_t)Y * 256) + X];
                    s += cv * bv * (1.f - mv);
                }
            }
        }
    }
    out[idx] = s;
}

// ---------------------------------------------------------------------------
extern "C" void kernel_launch(void* const* d_in, const int* in_sizes, int n_in,
                              void* d_out, int out_size, void* d_ws, size_t ws_size,
                              hipStream_t stream) {
    const float* cosp = (const float*)d_in[0];
    const float* bp   = (const float*)d_in[1];
    const float* mp   = (const float*)d_in[2];
    float* outp = (float*)d_out;

    const size_t cosT_f32_b = (size_t)4 * 1024 * 1024 * 4;       // 16.78 MB
    const size_t ct_b       = (size_t)4 * MPAD * KU * 2;         // 10.32 MB each (hi/lo)
    const size_t w2_b       = (size_t)4 * NTOT * KU * 2;         // 18.35 MB each (hi/lo)
    const size_t need2      = cosT_f32_b + ct_b * 2 + w2_b * 2;  // ~74.1 MB

    const size_t need1 = ((size_t)4 * L_DIM * SPA + (size_t)4 * MTOT * NTOT) * sizeof(float);

    if (ws_size >= need2) {
        char* p = (char*)d_ws;
        float*          cosT = (float*)p;          p += cosT_f32_b;
        unsigned short* c_hi = (unsigned short*)p; p += ct_b;
        unsigned short* c_lo = (unsigned short*)p; p += ct_b;
        unsigned short* w_hi = (unsigned short*)p; p += w2_b;
        unsigned short* w_lo = (unsigned short*)p;
        transpose_cos_k<<<dim3(32, 32, 4), dim3(32, 8), 0, stream>>>(cosp, cosT);
        build_ct_k<<<dim3(MPAD, 4), 256, 0, stream>>>(cosT, c_hi, c_lo);
        prep_w2_k<<<dim3(5, NTOT, 4), 256, 0, stream>>>(bp, mp, w_hi, w_lo);
        mfma_deconv2_k<<<576, 256, 0, stream>>>(c_hi, c_lo, w_hi, w_lo, outp);
    } else if (ws_size >= need1) {
        float* cosT = (float*)d_ws;
        float* W    = cosT + (size_t)4 * L_DIM * SPA;
        transpose_cos_k<<<dim3(32, 32, 4), dim3(32, 8), 0, stream>>>(cosp, cosT);
        const int wtot = 4 * MTOT * NTOT;
        build_w_k<<<(wtot + 255) / 256, 256, 0, stream>>>(bp, mp, W);
        gemm_deconv_k<<<dim3(32, 18, 4), dim3(256), 0, stream>>>(cosT, W, outp);
    } else {
        const int tot = 4 * 32 * 256 * 256;
        naive_deconv_k<<<(tot + 255) / 256, 256, 0, stream>>>(cosp, bp, mp, outp);
    }
}

// Round 9
// 233.380 us; speedup vs baseline: 5.0898x; 1.0870x over previous
//
#include <hip/hip_runtime.h>
#include <hip/hip_bf16.h>
#include <stdint.h>

#define L_DIM 1024
#define SPA   1024
#define MTOT  1089   // 33*33 output macro grid
#define NTOT  2048   // 32c * 8ry * 8rx
#define KU    1120   // u-dim padded (1089 -> 35*32)
#define MPAD  1152   // M padded to 9*128
#define NSTEP 105    // 3 terms * 35 K-chunks

typedef __attribute__((ext_vector_type(8))) short bf16x8;
typedef __attribute__((ext_vector_type(4))) float f32x4;

__device__ __forceinline__ unsigned short f2bf(float x) {
    __hip_bfloat16 h = __float2bfloat16(x);
    return *reinterpret_cast<unsigned short*>(&h);
}
__device__ __forceinline__ float bf2f(unsigned short u) {
    __hip_bfloat16 h;
    *reinterpret_cast<unsigned short*>(&h) = u;
    return __bfloat162float(h);
}

__device__ __forceinline__ void gload16(const void* g, void* l) {
    __builtin_amdgcn_global_load_lds(
        (const __attribute__((address_space(1))) unsigned int*)g,
        (__attribute__((address_space(3))) unsigned int*)l, 16, 0, 0);
}

// ---------------------------------------------------------------------------
// Stage 1: transpose cos (B,L=p,32,32) -> cosT f32 [b][s=iy*32+ix][p]
// ---------------------------------------------------------------------------
__global__ void transpose_cos_k(const float* __restrict__ src, float* __restrict__ dst) {
    __shared__ float tile[32][33];
    const int b  = blockIdx.z;
    const int l0 = blockIdx.x * 32;
    const int s0 = blockIdx.y * 32;
    const float* in  = src + (size_t)b * L_DIM * SPA;
    float*       out = dst + (size_t)b * L_DIM * SPA;
    const int tx = threadIdx.x, ty = threadIdx.y;
    #pragma unroll
    for (int i = ty; i < 32; i += 8)
        tile[i][tx] = in[(size_t)(l0 + i) * SPA + s0 + tx];
    __syncthreads();
    #pragma unroll
    for (int i = ty; i < 32; i += 8)
        out[(size_t)(s0 + i) * L_DIM + l0 + tx] = tile[tx][i];
}

// ---------------------------------------------------------------------------
// Stage 2: C'T[b][q][u] = sum_d cosT[b][q-d][u-d] (masked), split hi/lo bf16.
// Rows q in [1089,1152) and cols u>=1089 are zero (u>=1089 is zero naturally:
// uy=33 fails both d-masks). Grid (q=1152, b=4), 256 threads.
// ---------------------------------------------------------------------------
__global__ void build_ct_k(const float* __restrict__ cosT,
                           unsigned short* __restrict__ chi,
                           unsigned short* __restrict__ clo) {
    const int q = blockIdx.x;
    const int b = blockIdx.y;
    const size_t orow = ((size_t)b * MPAD + q) * KU;
    if (q >= MTOT) {
        for (int u = threadIdx.x; u < KU; u += 256) { chi[orow+u] = 0; clo[orow+u] = 0; }
        return;
    }
    const int qy = q / 33, qx = q - qy * 33;
    const float* rp[4];
    bool rv[4];
    #pragma unroll
    for (int d = 0; d < 4; ++d) {
        const int dy = d >> 1, dx = d & 1;
        const int sy = qy - dy, sx = qx - dx;
        rv[d] = ((unsigned)sy < 32u) && ((unsigned)sx < 32u);
        rp[d] = cosT + (((size_t)b * 1024) + sy * 32 + sx) * 1024;
    }
    for (int u = threadIdx.x; u < KU; u += 256) {
        const int uy = u / 33, ux = u - uy * 33;
        float v = 0.f;
        #pragma unroll
        for (int d = 0; d < 4; ++d) {
            const int dy = d >> 1, dx = d & 1;
            const int py = uy - dy, px = ux - dx;
            if (rv[d] && (unsigned)py < 32u && (unsigned)px < 32u)
                v += rp[d][py * 32 + px];
        }
        const unsigned short h = f2bf(v);
        chi[orow + u] = h;
        clo[orow + u] = f2bf(v - bf2f(h));
    }
}

// ---------------------------------------------------------------------------
// Stage 3 (REWRITTEN, coalesced): W[b][n][u] hi/lo bf16.
// For fixed (uy,ry): (ux,rx) -> X = 8*ux+rx-4 is a bijection onto one image
// row. Block per (b, c, uy*8+ry): load b-row & mask-row contiguously into
// LDS, compute w = b*(1-m), scatter 264 outputs (33-contig bf16 per rx).
// uy==32 blocks additionally zero the KU tail u in [1089,1120).
// ---------------------------------------------------------------------------
__global__ void prep_w3_k(const float* __restrict__ bsrc, const float* __restrict__ msrc,
                          unsigned short* __restrict__ whi, unsigned short* __restrict__ wlo) {
    __shared__ float wrow[256];
    const int uy = blockIdx.x >> 3, ry = blockIdx.x & 7;
    const int c  = blockIdx.y;
    const int b  = blockIdx.z;
    const int tid = threadIdx.x;
    int Y = 8 * uy + ry - 4;
    Y = min(max(Y, 0), 255);
    const float bv = bsrc[(((size_t)b * 32 + c) * 256 + Y) * 256 + tid];
    const float mv = msrc[((size_t)b * 256 + Y) * 256 + tid];
    wrow[tid] = bv * (1.f - mv);
    __syncthreads();
    const size_t nbase = (size_t)b * 2048 + c * 64 + ry * 8;
    for (int i = tid; i < 264; i += 256) {
        const int rx = i / 33, ux = i - rx * 33;
        int X = 8 * ux + rx - 4;
        X = min(max(X, 0), 255);
        const float v = wrow[X];
        const unsigned short h = f2bf(v);
        const size_t o = (nbase + rx) * KU + uy * 33 + ux;
        whi[o] = h;
        wlo[o] = f2bf(v - bf2f(h));
    }
    if (uy == 32) {   // zero the padding tail u in [1089,1120) for this block's 8 n-rows
        for (int i = tid; i < 8 * 31; i += 256) {
            const int rx = i / 31, j = i - rx * 31;
            const size_t o = (nbase + rx) * KU + MTOT + j;
            whi[o] = 0;
            wlo[o] = 0;
        }
    }
}

// ---------------------------------------------------------------------------
// Stage 4: MFMA GEMM, K=1120 x 3 split-terms = 105 flat steps. (unchanged)
// ---------------------------------------------------------------------------
__global__ __launch_bounds__(256, 3) void mfma_deconv2_k(
    const unsigned short* __restrict__ Ahi_, const unsigned short* __restrict__ Alo_,
    const unsigned short* __restrict__ Whi_, const unsigned short* __restrict__ Wlo_,
    float* __restrict__ out)
{
    __shared__ int lds_i[12288];           // 48 KB: 3 slots x (8KB A + 8KB B)
    char* lds = (char*)lds_i;

    // XCD-chunked bijective swizzle: grid 576 = 8 XCDs x 72 blocks.
    const int orig = blockIdx.x;
    const int wg   = (orig & 7) * 72 + (orig >> 3);
    const int bx   = wg & 15;            // n-tile [0,16)
    const int rem  = wg >> 4;            // [0,36)
    const int by   = rem % 9;            // m-tile [0,9)
    const int b    = rem / 9;            // batch [0,4)
    const int n_tile = bx * 128;
    const int m_tile = by * 128;

    const int tid  = threadIdx.x;
    const int lane = tid & 63;
    const int wave = tid >> 6;
    const int wr = wave >> 1, wc = wave & 1;

    const int row_in  = lane >> 2;                               // 0..15
    const int srcslot = ((lane & 3) ^ ((lane >> 3) & 3)) * 16;   // pre-swizzled src slot
    const int ml0 = wave * 32 + row_in;
    const int ml1 = ml0 + 16;

    const size_t aoff0 = ((size_t)(b * MPAD + m_tile + ml0)) * (KU * 2) + srcslot;
    const size_t aoff1 = ((size_t)(b * MPAD + m_tile + ml1)) * (KU * 2) + srcslot;
    const size_t boff0 = ((size_t)(b * NTOT + n_tile + ml0)) * (KU * 2) + srcslot;
    const size_t boff1 = ((size_t)(b * NTOT + n_tile + ml1)) * (KU * 2) + srcslot;

    const int dA0 = wave * 2048;
    const int dA1 = wave * 2048 + 1024;
    const int dB0 = 8192 + wave * 2048;
    const int dB1 = 8192 + wave * 2048 + 1024;

    const int fr = lane & 15;
    const int slotr = ((lane >> 4) ^ ((lane >> 1) & 3)) * 16;
    const int aoffs = (wr * 64 + fr) * 64 + slotr;
    const int boffs = 8192 + (wc * 64 + fr) * 64 + slotr;

    f32x4 acc[4][4] = {};

    const char *ap0, *ap1, *bp0, *bp1;
    int sw = 0, tt = 0;

    auto term_setup = [&](int t) {
        const char* Ab = (t == 1) ? (const char*)Alo_ : (const char*)Ahi_;
        const char* Bb = (t >= 2) ? (const char*)Wlo_ : (const char*)Whi_;
        ap0 = Ab + aoff0; ap1 = Ab + aoff1;
        bp0 = Bb + boff0; bp1 = Bb + boff1;
    };

    auto issue = [&](int slot) {
        char* sb_ = lds + slot * 16384;
        gload16(ap0, sb_ + dA0);
        gload16(ap1, sb_ + dA1);
        gload16(bp0, sb_ + dB0);
        gload16(bp1, sb_ + dB1);
        ap0 += 64; ap1 += 64; bp0 += 64; bp1 += 64;
        if (++sw == 35) {            // uniform branch at term boundary
            sw = 0;
            ++tt;                    // tt>=3: dummy re-stage (in-bounds, never read)
            term_setup(tt);
        }
    };

    term_setup(0);
    issue(0);
    issue(1);
    asm volatile("s_waitcnt vmcnt(4)" ::: "memory");
    __builtin_amdgcn_s_barrier();

    int cslot = 0, sslot = 2;
    for (int s = 0; s < NSTEP; ++s) {
        issue(sslot);
        const char* cb = lds + cslot * 16384;
        bf16x8 af[4], bfr[4];
        #pragma unroll
        for (int i = 0; i < 4; ++i) af[i]  = *(const bf16x8*)(cb + aoffs + i * 1024);
        #pragma unroll
        for (int j = 0; j < 4; ++j) bfr[j] = *(const bf16x8*)(cb + boffs + j * 1024);
        __builtin_amdgcn_s_setprio(1);
        #pragma unroll
        for (int i = 0; i < 4; ++i)
            #pragma unroll
            for (int j = 0; j < 4; ++j)
                acc[i][j] = __builtin_amdgcn_mfma_f32_16x16x32_bf16(
                    af[i], bfr[j], acc[i][j], 0, 0, 0);
        __builtin_amdgcn_s_setprio(0);
        asm volatile("s_waitcnt vmcnt(4)" ::: "memory");
        __builtin_amdgcn_s_barrier();
        cslot = (cslot == 2) ? 0 : cslot + 1;
        sslot = (sslot == 2) ? 0 : sslot + 1;
    }

    // Epilogue: C/D layout col=lane&15, row=(lane>>4)*4+reg. Crop [4:260).
    const int r0 = (lane >> 4) * 4;
    #pragma unroll
    for (int i = 0; i < 4; ++i) {
        #pragma unroll
        for (int r = 0; r < 4; ++r) {
            const int m = m_tile + wr * 64 + i * 16 + r0 + r;
            if (m >= MTOT) continue;
            const int qy2 = m / 33, qx2 = m - qy2 * 33;
            #pragma unroll
            for (int j = 0; j < 4; ++j) {
                const int n = n_tile + wc * 64 + j * 16 + fr;
                const int cch = n >> 6, ry = (n >> 3) & 7, rx = n & 7;
                const int y = qy2 * 8 + ry - 4;
                const int x = qx2 * 8 + rx - 4;
                if ((unsigned)y < 256u && (unsigned)x < 256u)
                    out[(((size_t)b * 32 + cch) * 256 + y) * 256 + x] = acc[i][j][r];
            }
        }
    }
}

// ===========================================================================
// Fallback path (fp32 GEMM, verified round 1) for smaller workspaces.
// ===========================================================================
__global__ void build_w_k(const float* __restrict__ bsrc, const float* __restrict__ msrc,
                          float* __restrict__ w) {
    const int total = 4 * MTOT * NTOT;
    const int idx = blockIdx.x * 256 + threadIdx.x;
    if (idx >= total) return;
    const int n = idx & (NTOT - 1);
    const int t = idx >> 11;
    const int p = t % MTOT;
    const int b = t / MTOT;
    const int px = p % 33, py = p / 33;
    const int c = n >> 6, ry = (n >> 3) & 7, rx = n & 7;
    int Y = 8 * py + ry - 4;
    int X = 8 * px + rx - 4;
    Y = min(max(Y, 0), 255);
    X = min(max(X, 0), 255);
    const float bv = bsrc[(((size_t)b * 32 + c) * 256 + Y) * 256 + X];
    const float mv = msrc[((size_t)b * 256 + Y) * 256 + X];
    w[idx] = bv * (1.0f - mv);
}

__global__ __launch_bounds__(256) void gemm_deconv_k(const float* __restrict__ cosT,
                                                     const float* __restrict__ W,
                                                     float* __restrict__ out) {
    __shared__ float As_[16][68];
    __shared__ float Bs_[16][64];
    const int b      = blockIdx.z;
    const int n_base = blockIdx.x * 64;
    const int m_base = blockIdx.y * 64;
    const int tid = threadIdx.x;
    const int tx = tid & 15;
    const int ty = tid >> 4;
    float acc[4][4] = {};
    const int arow = m_base + (tid >> 2);
    const int kl   = (tid & 3) * 4;
    const int qy   = arow / 33;
    const int qx   = arow - qy * 33;
    const int brow = tid >> 4;
    const int bcol = (tid & 15) * 4;
    for (int d = 0; d < 4; ++d) {
        const int dy = d >> 1, dx = d & 1;
        const int iy = qy - dy, ix = qx - dx;
        const bool avalid = (arow < MTOT) && ((unsigned)iy < 32u) && ((unsigned)ix < 32u);
        const float* aptr = cosT + (((size_t)b * 32 + iy) * 32 + ix) * L_DIM + kl;
        for (int k0 = 0; k0 < 1024; k0 += 16) {
            float4 av = make_float4(0.f, 0.f, 0.f, 0.f);
            if (avalid) av = *reinterpret_cast<const float4*>(aptr + k0);
            const int kp = k0 + brow;
            const int py = kp >> 5, px = kp & 31;
            const int wrow = (py + dy) * 33 + (px + dx);
            const float4 bv = *reinterpret_cast<const float4*>(
                W + ((size_t)b * MTOT + wrow) * NTOT + n_base + bcol);
            __syncthreads();
            As_[kl + 0][tid >> 2] = av.x;
            As_[kl + 1][tid >> 2] = av.y;
            As_[kl + 2][tid >> 2] = av.z;
            As_[kl + 3][tid >> 2] = av.w;
            *reinterpret_cast<float4*>(&Bs_[brow][bcol]) = bv;
            __syncthreads();
            #pragma unroll
            for (int k = 0; k < 16; ++k) {
                const float4 a  = *reinterpret_cast<const float4*>(&As_[k][ty * 4]);
                const float4 bb = *reinterpret_cast<const float4*>(&Bs_[k][tx * 4]);
                acc[0][0] += a.x * bb.x; acc[0][1] += a.x * bb.y;
                acc[0][2] += a.x * bb.z; acc[0][3] += a.x * bb.w;
                acc[1][0] += a.y * bb.x; acc[1][1] += a.y * bb.y;
                acc[1][2] += a.y * bb.z; acc[1][3] += a.y * bb.w;
                acc[2][0] += a.z * bb.x; acc[2][1] += a.z * bb.y;
                acc[2][2] += a.z * bb.z; acc[2][3] += a.z * bb.w;
                acc[3][0] += a.w * bb.x; acc[3][1] += a.w * bb.y;
                acc[3][2] += a.w * bb.z; acc[3][3] += a.w * bb.w;
            }
        }
    }
    #pragma unroll
    for (int i = 0; i < 4; ++i) {
        const int m = m_base + ty * 4 + i;
        if (m >= MTOT) continue;
        const int qy2 = m / 33, qx2 = m - qy2 * 33;
        #pragma unroll
        for (int j = 0; j < 4; ++j) {
            const int n = n_base + tx * 4 + j;
            const int c = n >> 6, ry = (n >> 3) & 7, rx = n & 7;
            const int y = qy2 * 8 + ry - 4;
            const int x = qx2 * 8 + rx - 4;
            if ((unsigned)y < 256u && (unsigned)x < 256u)
                out[(((size_t)b * 32 + c) * 256 + y) * 256 + x] = acc[i][j];
        }
    }
}

__global__ void naive_deconv_k(const float* __restrict__ cosp, const float* __restrict__ bsrc,
                               const float* __restrict__ msrc, float* __restrict__ out) {
    const int idx = blockIdx.x * 256 + threadIdx.x;
    if (idx >= 4 * 32 * 256 * 256) return;
    const int x = idx & 255, y = (idx >> 8) & 255, c = (idx >> 16) & 31, b = idx >> 21;
    const int oy = y + 4, ox = x + 4;
    const int qy = oy >> 3, ry = oy & 7, qx = ox >> 3, rx = ox & 7;
    float s = 0.f;
    for (int dy = 0; dy < 2; ++dy) {
        for (int dx = 0; dx < 2; ++dx) {
            const int iy = qy - dy, ix = qx - dx;
            if ((unsigned)iy >= 32u || (unsigned)ix >= 32u) continue;
            for (int py = 0; py < 32; ++py) {
                int Y = 8 * (py + dy) + ry - 4;
                Y = min(max(Y, 0), 255);
                for (int px = 0; px < 32; ++px) {
                    int X = 8 * (px + dx) + rx - 4;
                    X = min(max(X, 0), 255);
                    const float cv = cosp[(((size_t)(b * 1024 + py * 32 + px)) * 32 + iy) * 32 + ix];
                    const float bv = bsrc[(((size_t)(b * 32 + c)) * 256 + Y) * 256 + X];
                    const float mv = msrc[((size_t)b * 65536 + (size_t)Y * 256) + X];
                    s += cv * bv * (1.f - mv);
                }
            }
        }
    }
    out[idx] = s;
}

// ---------------------------------------------------------------------------
extern "C" void kernel_launch(void* const* d_in, const int* in_sizes, int n_in,
                              void* d_out, int out_size, void* d_ws, size_t ws_size,
                              hipStream_t stream) {
    const float* cosp = (const float*)d_in[0];
    const float* bp   = (const float*)d_in[1];
    const float* mp   = (const float*)d_in[2];
    float* outp = (float*)d_out;

    const size_t cosT_f32_b = (size_t)4 * 1024 * 1024 * 4;       // 16.78 MB
    const size_t ct_b       = (size_t)4 * MPAD * KU * 2;         // 10.32 MB each (hi/lo)
    const size_t w2_b       = (size_t)4 * NTOT * KU * 2;         // 18.35 MB each (hi/lo)
    const size_t need2      = cosT_f32_b + ct_b * 2 + w2_b * 2;  // ~74.1 MB

    const size_t need1 = ((size_t)4 * L_DIM * SPA + (size_t)4 * MTOT * NTOT) * sizeof(float);

    if (ws_size >= need2) {
        char* p = (char*)d_ws;
        float*          cosT = (float*)p;          p += cosT_f32_b;
        unsigned short* c_hi = (unsigned short*)p; p += ct_b;
        unsigned short* c_lo = (unsigned short*)p; p += ct_b;
        unsigned short* w_hi = (unsigned short*)p; p += w2_b;
        unsigned short* w_lo = (unsigned short*)p;
        transpose_cos_k<<<dim3(32, 32, 4), dim3(32, 8), 0, stream>>>(cosp, cosT);
        build_ct_k<<<dim3(MPAD, 4), 256, 0, stream>>>(cosT, c_hi, c_lo);
        prep_w3_k<<<dim3(264, 32, 4), 256, 0, stream>>>(bp, mp, w_hi, w_lo);
        mfma_deconv2_k<<<576, 256, 0, stream>>>(c_hi, c_lo, w_hi, w_lo, outp);
    } else if (ws_size >= need1) {
        float* cosT = (float*)d_ws;
        float* W    = cosT + (size_t)4 * L_DIM * SPA;
        transpose_cos_k<<<dim3(32, 32, 4), dim3(32, 8), 0, stream>>>(cosp, cosT);
        const int wtot = 4 * MTOT * NTOT;
        build_w_k<<<(wtot + 255) / 256, 256, 0, stream>>>(bp, mp, W);
        gemm_deconv_k<<<dim3(32, 18, 4), dim3(256), 0, stream>>>(cosT, W, outp);
    } else {
        const int tot = 4 * 32 * 256 * 256;
        naive_deconv_k<<<(tot + 255) / 256, 256, 0, stream>>>(cosp, bp, mp, outp);
    }
}